// Round 1
// baseline (84.282 us; speedup 1.0000x reference)
//
#include <hip/hip_runtime.h>

#define N  32
#define NN (N * N)

// One block per batch element; one thread per grid cell.
// Bellman-Ford chaotic relaxation to fixpoint in LDS. fp32 add of
// non-negative weights is monotone, so the fixpoint of
//   dist[v] = min_u (dist[u] + w[v])
// is bitwise-identical to the reference's Dijkstra distances (same fp ops).
// Predecessors recovered as argmin_u(dist[u] + w[v]); path traced serially.
__global__ __launch_bounds__(NN, 1) void dijkstra_path_kernel(
    const float* __restrict__ weights, float* __restrict__ out)
{
    const int b = blockIdx.x;
    const int t = threadIdx.x;          // flat cell index, 0..1023
    const int y = t >> 5;
    const int x = t & 31;

    __shared__ float dist[NN];
    __shared__ int   pred[NN];
    __shared__ unsigned char pathm[NN];

    const float INF = __builtin_huge_valf();
    const float wme = weights[b * NN + t];   // cost of entering this cell

    dist[t]  = (t == 0) ? 0.0f : INF;
    pathm[t] = 0;

    // Precompute the 8 neighbor flat indices; invalid -> self (self never
    // improves since w > 0 and reads of self are harmless upper bounds).
    const int dyv[8] = {-1, 1, 0, 0, -1, -1, 1, 1};
    const int dxv[8] = { 0, 0,-1, 1, -1,  1,-1, 1};
    int nbr[8];
    unsigned validm = 0;
    #pragma unroll
    for (int k = 0; k < 8; ++k) {
        int ny = y + dyv[k], nx = x + dxv[k];
        bool ok = (ny >= 0) && (ny < N) && (nx >= 0) && (nx < N);
        nbr[k] = ok ? (ny * N + nx) : t;
        if (ok) validm |= (1u << k);
    }
    __syncthreads();

    // Chaotic relaxation. One barrier per sweep (the __syncthreads_or).
    // Intra-sweep races are safe: dist values only decrease and never
    // undershoot the fixpoint; a full sweep with zero changes after a
    // barrier certifies the Bellman fixpoint.
    for (int it = 0; it < 4096; ++it) {
        float old = dist[t];
        float v = old;
        #pragma unroll
        for (int k = 0; k < 8; ++k)
            v = fminf(v, dist[nbr[k]] + wme);
        int changed = (v < old) ? 1 : 0;
        if (changed) dist[t] = v;
        if (__syncthreads_or(changed) == 0) break;
    }

    // Predecessor of each cell: the neighbor achieving dist[v] (unique for
    // generic random weights). Source keeps pred = 0 (fixed point).
    int p = 0;
    if (t != 0) {
        float best = INF;
        #pragma unroll
        for (int k = 0; k < 8; ++k) {
            if (validm & (1u << k)) {
                float c = dist[nbr[k]] + wme;
                if (c < best) { best = c; p = nbr[k]; }
            }
        }
    }
    pred[t] = p;
    __syncthreads();

    // Serial backtrack from target (31,31) to source (0,0).
    if (t == 0) {
        int cur = NN - 1;
        pathm[cur] = 1;
        for (int s = 0; s < NN && cur != 0; ++s) {
            cur = pred[cur];
            pathm[cur] = 1;
        }
    }
    __syncthreads();

    out[b * NN + t] = pathm[t] ? 1.0f : 0.0f;
}

extern "C" void kernel_launch(void* const* d_in, const int* in_sizes, int n_in,
                              void* d_out, int out_size, void* d_ws, size_t ws_size,
                              hipStream_t stream) {
    const float* w = (const float*)d_in[0];
    float* out = (float*)d_out;
    const int b = in_sizes[0] / NN;   // 128
    dijkstra_path_kernel<<<dim3(b), dim3(NN), 0, stream>>>(w, out);
}

// Round 3
// 74.433 us; speedup vs baseline: 1.1323x; 1.1323x over previous
//
#include <hip/hip_runtime.h>

#define N   32
#define NN  1024
#define PS  34              // padded LDS stride (+2 border; 2-way bank alias only = free)
#define PSZ (PS * PS)       // 1156

// One WAVE (64 lanes) per batch element. Lane (ty,tx) owns a 4x4 cell tile in
// registers (interior of a 6x6 block g); the border of g is the halo, re-read
// from LDS each sweep. LDS dist is padded 34x34 with an INF border so boundary
// handling is free. Per sweep: 20 halo reads, in-register Gauss-Seidel
// (forward + backward raster), 16 write-backs, one __syncthreads.
//
// The __syncthreads per sweep is REQUIRED even for a single wave: it is the
// compiler memory fence that stops LLVM from caching the halo loads across
// iterations (R2 failed exactly this way). HW-wise a single wave's DS ops are
// in-order, so the barrier cost is just s_waitcnt lgkmcnt(0) (+ s_barrier).
//
// Bitwise-exactness: every value ever assigned is an fp-fold of some path from
// the source; the monotone-decreasing chaotic/GS iteration from INF converges
// to min-over-paths of the fold regardless of order — identical to the
// reference's Dijkstra fp ops (validated absmax=0 in R1 with Jacobi order).
__global__ __launch_bounds__(64, 1) void dijkstra_path_kernel(
    const float* __restrict__ weights, float* __restrict__ out)
{
    const int b    = blockIdx.x;
    const int lane = threadIdx.x;      // 0..63
    const int ty   = lane >> 3;        // tile row 0..7
    const int tx   = lane & 7;         // tile col 0..7
    const int y0   = ty << 2;          // tile origin (global cell coords)
    const int x0   = tx << 2;

    __shared__ float dist[PSZ];        // padded: P(y,x) = (y+1)*34 + (x+1)
    __shared__ int   pred[NN];
    __shared__ float pathf[NN];

    const float INF = __builtin_huge_valf();

    // ---- init LDS: dist = INF everywhere (incl. border), pathf = 0 ----
    #pragma unroll
    for (int k = 0; k < 19; ++k) {
        int idx = lane + k * 64;
        if (idx < PSZ) dist[idx] = INF;
    }
    #pragma unroll
    for (int k = 0; k < 16; ++k) pathf[lane + k * 64] = 0.0f;

    // ---- weights tile -> registers (float4 rows) ----
    float w[4][4];
    const float* wb = weights + b * NN;
    #pragma unroll
    for (int i = 0; i < 4; ++i) {
        const float4 v = *(const float4*)(wb + (y0 + i) * N + x0);
        w[i][0] = v.x; w[i][1] = v.y; w[i][2] = v.z; w[i][3] = v.w;
    }

    // ---- register state: 6x6 (interior = my 4x4 tile, border = halo) ----
    float g[6][6];
    #pragma unroll
    for (int i = 0; i < 6; ++i)
        #pragma unroll
        for (int j = 0; j < 6; ++j) g[i][j] = INF;
    if (lane == 0) {
        g[1][1] = 0.0f;
        dist[1 * PS + 1] = 0.0f;       // source visible to neighbors at sweep 1
    }
    __syncthreads();                   // init (incl. cross-lane INF fill) visible

    // ---- relaxation sweeps ----
    const int base_top = y0 * PS + x0;            // P(y0-1, x0-1)
    const int base_bot = (y0 + 5) * PS + x0;      // P(y0+4, x0-1)
    for (int it = 0; it < 512; ++it) {
        // halo -> g border (previous sweep's values; fenced by __syncthreads)
        #pragma unroll
        for (int j = 0; j < 6; ++j) g[0][j] = dist[base_top + j];
        #pragma unroll
        for (int j = 0; j < 6; ++j) g[5][j] = dist[base_bot + j];
        #pragma unroll
        for (int i = 0; i < 4; ++i) {
            g[1 + i][0] = dist[(y0 + i + 1) * PS + x0];      // P(y0+i, x0-1)
            g[1 + i][5] = dist[(y0 + i + 1) * PS + x0 + 5];  // P(y0+i, x0+4)
        }

        bool changed = false;
        // forward Gauss-Seidel raster
        #pragma unroll
        for (int i = 1; i <= 4; ++i)
            #pragma unroll
            for (int j = 1; j <= 4; ++j) {
                float m = fminf(
                    fminf(fminf(g[i-1][j-1], g[i-1][j]), fminf(g[i-1][j+1], g[i][j-1])),
                    fminf(fminf(g[i][j+1], g[i+1][j-1]), fminf(g[i+1][j], g[i+1][j+1])));
                float nv = m + w[i-1][j-1];
                if (nv < g[i][j]) { g[i][j] = nv; changed = true; }
            }
        // backward Gauss-Seidel raster
        #pragma unroll
        for (int i = 4; i >= 1; --i)
            #pragma unroll
            for (int j = 4; j >= 1; --j) {
                float m = fminf(
                    fminf(fminf(g[i-1][j-1], g[i-1][j]), fminf(g[i-1][j+1], g[i][j-1])),
                    fminf(fminf(g[i][j+1], g[i+1][j-1]), fminf(g[i+1][j], g[i+1][j+1])));
                float nv = m + w[i-1][j-1];
                if (nv < g[i][j]) { g[i][j] = nv; changed = true; }
            }

        // write back interior (skip if unchanged -> LDS already current)
        if (changed) {
            #pragma unroll
            for (int i = 0; i < 4; ++i)
                #pragma unroll
                for (int j = 0; j < 4; ++j)
                    dist[(y0 + i + 1) * PS + (x0 + j + 1)] = g[1 + i][1 + j];
        }
        __syncthreads();               // fence: publish writes, force halo reload
        if (!__any((int)changed)) break;
    }

    // ---- predecessors: argmin over 8 neighbors of fp(dist_u + w_v), DIRS order ----
    // (g border = final halo: the terminating sweep saw no changes anywhere)
    const int dy[8] = {-1, 1, 0, 0, -1, -1, 1, 1};
    const int dx[8] = { 0, 0,-1, 1, -1,  1,-1, 1};
    #pragma unroll
    for (int i = 0; i < 4; ++i)
        #pragma unroll
        for (int j = 0; j < 4; ++j) {
            const int yy = y0 + i, xx = x0 + j;
            const int t  = yy * N + xx;
            int p = 0;
            if (t != 0) {
                float best = INF;
                #pragma unroll
                for (int k = 0; k < 8; ++k) {
                    float u = g[1 + i + dy[k]][1 + j + dx[k]];   // OOB -> INF border
                    float c = u + w[i][j];
                    if (c < best) { best = c; p = (yy + dy[k]) * N + (xx + dx[k]); }
                }
            }
            pred[t] = p;
        }
    __syncthreads();                   // pred visible to lane 0

    // ---- serial backtrack from (31,31); pred[0]==0 is the fixed point ----
    if (lane == 0) {
        int cur = NN - 1;
        pathf[cur] = 1.0f;
        for (int s = 0; s < NN && cur != 0; ++s) {
            cur = pred[cur];
            pathf[cur] = 1.0f;
        }
    }
    __syncthreads();                   // lane 0's path writes visible to all

    // ---- write output (float4 rows) ----
    float* ob = out + b * NN;
    #pragma unroll
    for (int i = 0; i < 4; ++i) {
        const int t = (y0 + i) * N + x0;
        float4 v = *(float4*)&pathf[t];
        *(float4*)(ob + t) = v;
    }
}

extern "C" void kernel_launch(void* const* d_in, const int* in_sizes, int n_in,
                              void* d_out, int out_size, void* d_ws, size_t ws_size,
                              hipStream_t stream) {
    const float* w = (const float*)d_in[0];
    float* out = (float*)d_out;
    const int b = in_sizes[0] / NN;   // 128
    dijkstra_path_kernel<<<dim3(b), dim3(64), 0, stream>>>(w, out);
}

// Round 4
// 72.576 us; speedup vs baseline: 1.1613x; 1.0256x over previous
//
#include <hip/hip_runtime.h>

#define N   32
#define NN  1024
#define PS  34              // padded LDS stride (+2 border; aliasing is 2-way = free)
#define PSZ (PS * PS)       // 1156

// One WAVE (64 lanes) per batch element. Lane (ty,tx) owns a 4x4 cell tile in
// registers (interior of a 6x6 block g); border of g = halo re-read from LDS
// each sweep. LDS dist is padded 34x34 with an INF border so boundary handling
// is free. Per sweep: vectorized halo reads (b128/b64/read2), in-register
// Gauss-Seidel (fwd + bwd raster, ILP-restructured), paired write-backs, one
// __threadfence_block.
//
// Fence discipline (R2 failed without it): __threadfence_block is the compiler
// memory fence + lgkmcnt drain. No s_barrier needed: the block is ONE wave and
// a wave's DS instructions execute in order on the LDS pipe, so cross-lane
// read-after-write through LDS is HW-correct; the fence only stops LLVM from
// caching halo loads across sweeps.
//
// Bitwise-exactness: every assigned value is an fp-fold of a source path;
// monotone-decreasing chaotic/GS iteration from INF converges to the unique
// fixpoint = min-over-paths fold, identical to the reference's Dijkstra fp ops
// (validated absmax=0 in R1 Jacobi order and R3 GS order).
__global__ __launch_bounds__(64, 1) void dijkstra_path_kernel(
    const float* __restrict__ weights, float* __restrict__ out)
{
    const int b    = blockIdx.x;
    const int lane = threadIdx.x & 63;
    const int ty   = lane >> 3;        // tile row 0..7
    const int tx   = lane & 7;         // tile col 0..7
    const int y0   = ty << 2;          // tile origin (global cell coords)
    const int x0   = tx << 2;

    __shared__ float dist[PSZ];        // P(y,x) = (y+1)*34 + (x+1)
    __shared__ int   pred[NN];
    __shared__ float pathf[NN];

    const float INF = __builtin_huge_valf();

    // ---- init LDS: dist = INF everywhere (incl. border), pathf = 0 ----
    #pragma unroll
    for (int k = 0; k < 19; ++k) {
        int idx = lane + k * 64;
        if (idx < PSZ) dist[idx] = INF;
    }
    #pragma unroll
    for (int k = 0; k < 16; ++k) pathf[lane + k * 64] = 0.0f;

    // ---- weights tile -> registers (float4 rows) ----
    float w[4][4];
    const float* wb = weights + b * NN;
    #pragma unroll
    for (int i = 0; i < 4; ++i) {
        const float4 v = *(const float4*)(wb + (y0 + i) * N + x0);
        w[i][0] = v.x; w[i][1] = v.y; w[i][2] = v.z; w[i][3] = v.w;
    }

    // ---- register state: 6x6 (interior = my 4x4 tile, border = halo) ----
    float g[6][6];
    #pragma unroll
    for (int i = 0; i < 6; ++i)
        #pragma unroll
        for (int j = 0; j < 6; ++j) g[i][j] = INF;
    if (lane == 0) {
        g[1][1] = 0.0f;
        dist[1 * PS + 1] = 0.0f;       // source visible to neighbors at sweep 1
    }
    __threadfence_block();             // publish init

    // ---- relaxation sweeps ----
    const int base_top = y0 * PS + x0;            // P(y0-1, x0-1); == 0 (mod 4)
    const int base_bot = (y0 + 5) * PS + x0;      // P(y0+4, x0-1); == 2 (mod 4)
    for (int it = 0; it < 256; ++it) {
        // top halo: aligned float4 + float2
        {
            const float4 a = *(const float4*)&dist[base_top];
            g[0][0] = a.x; g[0][1] = a.y; g[0][2] = a.z; g[0][3] = a.w;
            const float2 c = *(const float2*)&dist[base_top + 4];
            g[0][4] = c.x; g[0][5] = c.y;
        }
        // bottom halo: two aligned float4 straddling base_bot; keep cols x0-1..x0+4.
        // base_bot-2 >= 168 (in-bounds); over-read slop is discarded.
        {
            const float4 a = *(const float4*)&dist[base_bot - 2];
            const float4 c = *(const float4*)&dist[base_bot + 2];
            g[5][0] = a.z; g[5][1] = a.w;
            g[5][2] = c.x; g[5][3] = c.y; g[5][4] = c.z; g[5][5] = c.w;
        }
        // side halos: per-row pairs (offset 0 and 5) -> ds_read2_b32
        #pragma unroll
        for (int i = 0; i < 4; ++i) {
            const int r = (y0 + i + 1) * PS + x0;
            g[1 + i][0] = dist[r];
            g[1 + i][5] = dist[r + 5];
        }

        bool changed = false;
        // forward Gauss-Seidel raster. For cell (i,j) the only values that
        // change during this raster before it is processed are row i-1 and
        // the left neighbor; everything else is precomputable per row (ILP).
        #pragma unroll
        for (int i = 1; i <= 4; ++i) {
            float pre[4];
            #pragma unroll
            for (int j = 1; j <= 4; ++j)
                pre[j - 1] = fminf(fminf(g[i][j + 1], g[i + 1][j - 1]),
                                   fminf(g[i + 1][j], g[i + 1][j + 1]));
            #pragma unroll
            for (int j = 1; j <= 4; ++j) {
                const float u = fminf(fminf(g[i - 1][j - 1], g[i - 1][j]), g[i - 1][j + 1]);
                const float m = fminf(fminf(u, pre[j - 1]), g[i][j - 1]);
                const float nv = m + w[i - 1][j - 1];
                if (nv < g[i][j]) { g[i][j] = nv; changed = true; }
            }
        }
        // backward raster (mirror): dynamic deps = row i+1 and right neighbor.
        #pragma unroll
        for (int i = 4; i >= 1; --i) {
            float pre[4];
            #pragma unroll
            for (int j = 4; j >= 1; --j)
                pre[j - 1] = fminf(fminf(g[i - 1][j - 1], g[i - 1][j]),
                                   fminf(g[i - 1][j + 1], g[i][j - 1]));
            #pragma unroll
            for (int j = 4; j >= 1; --j) {
                const float d = fminf(fminf(g[i + 1][j - 1], g[i + 1][j]), g[i + 1][j + 1]);
                const float m = fminf(fminf(d, pre[j - 1]), g[i][j + 1]);
                const float nv = m + w[i - 1][j - 1];
                if (nv < g[i][j]) { g[i][j] = nv; changed = true; }
            }
        }

        // unconditional write-back; adjacent pairs fuse to ds_write2_b32
        #pragma unroll
        for (int i = 0; i < 4; ++i) {
            const int r = (y0 + i + 1) * PS + (x0 + 1);
            dist[r]     = g[1 + i][1];
            dist[r + 1] = g[1 + i][2];
            dist[r + 2] = g[1 + i][3];
            dist[r + 3] = g[1 + i][4];
        }
        __threadfence_block();         // publish writes, force halo reload
        if (!__any((int)changed)) break;
    }

    // ---- predecessors: argmin over 8 neighbors of fp(dist_u + w_v), DIRS order ----
    // (g border = final halo: the terminating sweep saw no changes anywhere)
    const int dy[8] = {-1, 1, 0, 0, -1, -1, 1, 1};
    const int dx[8] = { 0, 0,-1, 1, -1,  1,-1, 1};
    #pragma unroll
    for (int i = 0; i < 4; ++i)
        #pragma unroll
        for (int j = 0; j < 4; ++j) {
            const int yy = y0 + i, xx = x0 + j;
            const int t  = yy * N + xx;
            int p = 0;
            if (t != 0) {
                float best = INF;
                #pragma unroll
                for (int k = 0; k < 8; ++k) {
                    const float u = g[1 + i + dy[k]][1 + j + dx[k]];  // OOB -> INF border
                    const float c = u + w[i][j];
                    if (c < best) { best = c; p = (yy + dy[k]) * N + (xx + dx[k]); }
                }
            }
            pred[t] = p;
        }
    __threadfence_block();             // pred visible to lane 0

    // ---- serial backtrack from (31,31); pred[0]==0 is the fixed point ----
    if (lane == 0) {
        int cur = NN - 1;
        pathf[cur] = 1.0f;
        for (int s = 0; s < NN && cur != 0; ++s) {
            cur = pred[cur];
            pathf[cur] = 1.0f;
        }
    }
    __threadfence_block();             // lane 0's path writes visible to all

    // ---- write output (float4 rows) ----
    float* ob = out + b * NN;
    #pragma unroll
    for (int i = 0; i < 4; ++i) {
        const int t = (y0 + i) * N + x0;
        const float4 v = *(const float4*)&pathf[t];
        *(float4*)(ob + t) = v;
    }
}

extern "C" void kernel_launch(void* const* d_in, const int* in_sizes, int n_in,
                              void* d_out, int out_size, void* d_ws, size_t ws_size,
                              hipStream_t stream) {
    const float* w = (const float*)d_in[0];
    float* out = (float*)d_out;
    const int b = in_sizes[0] / NN;   // 128
    dijkstra_path_kernel<<<dim3(b), dim3(64), 0, stream>>>(w, out);
}